// Round 6
// baseline (276.144 us; speedup 1.0000x reference)
//
#include <hip/hip_runtime.h>

#define NN 50000

typedef __bf16 bf16x8 __attribute__((ext_vector_type(8)));
typedef float f32x4 __attribute__((ext_vector_type(4)));

__device__ __forceinline__ unsigned short f2bf(float f) {
    unsigned int u = __builtin_bit_cast(unsigned int, f);
    u += 0x7FFF + ((u >> 16) & 1);  // round-to-nearest-even
    return (unsigned short)(u >> 16);
}
__device__ __forceinline__ float bf2f(unsigned short h) {
    unsigned int u = ((unsigned int)h) << 16;
    return __builtin_bit_cast(float, u);
}
__device__ __forceinline__ void gload16(const void* g, void* l) {
    __builtin_amdgcn_global_load_lds(
        (const __attribute__((address_space(1))) unsigned int*)g,
        (__attribute__((address_space(3))) unsigned int*)l, 16, 0, 0);
}

// ---------------- edge dtype detection ----------------
__global__ void detect_kernel(const int* __restrict__ ei32, int* __restrict__ flag) {
    __shared__ int red[256];
    int tid = threadIdx.x;
    int o = 0;
    for (int i = tid; i < 4096; i += 256) o |= ei32[2 * i + 1];
    red[tid] = o;
    __syncthreads();
    for (int s = 128; s > 0; s >>= 1) {
        if (tid < s) red[tid] |= red[tid + s];
        __syncthreads();
    }
    if (tid == 0) *flag = (red[0] == 0) ? 1 : 0;
}

__device__ __forceinline__ int load_edge(const void* ei, int is64, long long idx) {
    return is64 ? (int)((const long long*)ei)[idx] : ((const int*)ei)[idx];
}

// ---------------- CSR build ----------------
__global__ void hist_kernel(const void* __restrict__ ei, const int* __restrict__ flag,
                            int* __restrict__ cnt, int E) {
    int e = blockIdx.x * blockDim.x + threadIdx.x;
    if (e >= E) return;
    int is64 = *flag;
    int dst = load_edge(ei, is64, (long long)E + e);
    atomicAdd(&cnt[dst], 1);
}

// pass 1: block b reduces cnt[b*1024 .. b*1024+1023] -> bsum[b]
__global__ void scan_part(const int* __restrict__ cnt, int* __restrict__ bsum, int n) {
    __shared__ int s[256];
    const int tid = threadIdx.x;
    const int i0 = blockIdx.x * 1024 + tid * 4;
    int sum = 0;
#pragma unroll
    for (int j = 0; j < 4; ++j) {
        int i = i0 + j;
        if (i < n) sum += cnt[i];
    }
    s[tid] = sum;
    __syncthreads();
    for (int o = 128; o > 0; o >>= 1) {
        if (tid < o) s[tid] += s[tid + o];
        __syncthreads();
    }
    if (tid == 0) bsum[blockIdx.x] = s[0];
}

// pass 2: one wave turns bsum[] (nb <= 64) into its exclusive scan; off[n] = total
__global__ void scan_top(int* __restrict__ bsum, int* __restrict__ off, int nb, int n) {
    const int lane = threadIdx.x & 63;
    int mine = (lane < nb) ? bsum[lane] : 0;
    int v = mine;
#pragma unroll
    for (int o = 1; o < 64; o <<= 1) {
        int t = __shfl_up(v, o, 64);
        if (lane >= o) v += t;
    }
    if (lane < nb) bsum[lane] = v - mine;  // exclusive prefix
    if (lane == 63) off[n] = v;            // grand total
}

// pass 3: block b scans its 1024 counts with base bsum[b]; writes off/pos
__global__ void scan_fin(const int* __restrict__ cnt, const int* __restrict__ bsum,
                         int* __restrict__ off, int* __restrict__ pos, int n) {
    __shared__ int s[256];
    const int tid = threadIdx.x;
    const int i0 = blockIdx.x * 1024 + tid * 4;
    int v[4];
    int sum = 0;
#pragma unroll
    for (int j = 0; j < 4; ++j) {
        int i = i0 + j;
        v[j] = (i < n) ? cnt[i] : 0;
        sum += v[j];
    }
    s[tid] = sum;
    __syncthreads();
    for (int o = 1; o < 256; o <<= 1) {
        int t = 0;
        if (tid >= o) t = s[tid - o];
        __syncthreads();
        s[tid] += t;
        __syncthreads();
    }
    int run = bsum[blockIdx.x] + s[tid] - sum;  // exclusive within grid
#pragma unroll
    for (int j = 0; j < 4; ++j) {
        int i = i0 + j;
        if (i < n) {
            off[i] = run;
            pos[i] = run;
            run += v[j];
        }
    }
}

__global__ void fill_kernel(const void* __restrict__ ei, const int* __restrict__ flag,
                            int* __restrict__ pos, int* __restrict__ adj, int E) {
    int e = blockIdx.x * blockDim.x + threadIdx.x;
    if (e >= E) return;
    int is64 = *flag;
    int src = load_edge(ei, is64, e);
    int dst = load_edge(ei, is64, (long long)E + e);
    int p = atomicAdd(&pos[dst], 1);
    adj[p] = src;
}

// ---------------- f32 -> bf16 convert ----------------
__global__ void cvt_bf16(const float* __restrict__ in, unsigned short* __restrict__ out, int n4) {
    int i = blockIdx.x * blockDim.x + threadIdx.x;
    if (i >= n4) return;
    float4 v = ((const float4*)in)[i];
    uint2 o;
    o.x = (unsigned int)f2bf(v.x) | ((unsigned int)f2bf(v.y) << 16);
    o.y = (unsigned int)f2bf(v.z) | ((unsigned int)f2bf(v.w) << 16);
    ((uint2*)out)[i] = o;
}

// ---------------- weight prep: Wt[c][k] = bf16([Wl; Wr][k][c]) ----------------
__global__ void prep_w(const float* __restrict__ Wl, const float* __restrict__ Wr,
                       unsigned short* __restrict__ Wt, int KH) {
    int c = blockIdx.x;  // 0..255
    int KC = 2 * KH;
    for (int k = threadIdx.x; k < KC; k += blockDim.x) {
        float v = (k < KH) ? Wl[(size_t)k * 256 + c] : Wr[(size_t)(k - KH) * 256 + c];
        Wt[(size_t)c * KC + k] = f2bf(v);
    }
}

// ---------------- mean aggregation, bf16 in/out, one wave per node ----------------
// Edge loop unrolled x4 with independent accumulators -> 4 row-gathers in flight (MLP=4).
template <int VPL>  // values per lane; F = 64*VPL
__global__ void agg_bf(const unsigned short* __restrict__ feat, const int* __restrict__ off,
                       const int* __restrict__ adj, unsigned short* __restrict__ out, int n) {
    int node = blockIdx.x * 4 + (threadIdx.x >> 6);
    if (node >= n) return;
    const int lane = threadIdx.x & 63;
    constexpr int F = 64 * VPL;
    const int s = off[node], e = off[node + 1];

    float a0[VPL] = {}, a1[VPL] = {}, a2[VPL] = {}, a3[VPL] = {};

    auto addrow = [&](float* acc, int src) {
        const unsigned short* p = feat + (size_t)src * F + lane * VPL;
        if constexpr (VPL == 2) {
            unsigned int v = *(const unsigned int*)p;
            acc[0] += bf2f((unsigned short)(v & 0xffff));
            acc[1] += bf2f((unsigned short)(v >> 16));
        } else {
            uint2 v = *(const uint2*)p;
            acc[0] += bf2f((unsigned short)(v.x & 0xffff));
            acc[1] += bf2f((unsigned short)(v.x >> 16));
            acc[2] += bf2f((unsigned short)(v.y & 0xffff));
            acc[3] += bf2f((unsigned short)(v.y >> 16));
        }
    };

    int j = s;
    for (; j + 4 <= e; j += 4) {
        int i0 = adj[j], i1 = adj[j + 1], i2 = adj[j + 2], i3 = adj[j + 3];
        addrow(a0, i0);
        addrow(a1, i1);
        addrow(a2, i2);
        addrow(a3, i3);
    }
    // tail (<=3), still independent accumulators
    {
        int rem = e - j;
        if (rem > 0) addrow(a0, adj[j]);
        if (rem > 1) addrow(a1, adj[j + 1]);
        if (rem > 2) addrow(a2, adj[j + 2]);
    }

    int deg = e - s;
    float inv = 1.0f / (float)(deg > 0 ? deg : 1);
#pragma unroll
    for (int k = 0; k < VPL; ++k) a0[k] = (a0[k] + a1[k] + a2[k] + a3[k]) * inv;

    if constexpr (VPL == 2) {
        unsigned int o = (unsigned int)f2bf(a0[0]) | ((unsigned int)f2bf(a0[1]) << 16);
        *(unsigned int*)(out + (size_t)node * F + lane * 2) = o;
    } else {
        uint2 o;
        o.x = (unsigned int)f2bf(a0[0]) | ((unsigned int)f2bf(a0[1]) << 16);
        o.y = (unsigned int)f2bf(a0[2]) | ((unsigned int)f2bf(a0[3]) << 16);
        *(uint2*)(out + (size_t)node * F + lane * 4) = o;
    }
}

// ---------------- fused SAGE MFMA GEMM (32-row tiles, whole-K preload) ----------------
// C[32 x 256] per block, 4 waves, wave w owns cols [64w, 64w+64).
// Whole A panel (32 x KC) staged via global_load_lds (wave w stages steps [w*SPW, w*SPW+SPW),
// 2 gloads each -> deep MLP), ONE barrier, then a barrier-free K-loop the compiler can
// software-pipeline. 32-row tiles keep LDS at 16/32KB -> 4-6 blocks/CU for TLP latency hiding.
template <int KH, bool L0>
__global__ __launch_bounds__(256, 4) void sage_mfma(
    const unsigned short* __restrict__ Aagg, const unsigned short* __restrict__ Axin,
    const unsigned short* __restrict__ Wt, const float* __restrict__ bl,
    const float* __restrict__ bng, const float* __restrict__ bnb,
    const float* __restrict__ bnm, const float* __restrict__ bnv,
    unsigned short* __restrict__ hout, float* __restrict__ fout, int n) {
    constexpr int KC = 2 * KH;
    constexpr int NSTEP = KC / 32;   // 8 (L0) or 16 (L1)
    constexpr int SPW = NSTEP / 4;   // steps staged per wave
    // [step][kgrp][row][8] : L1 = 32KB, L0 = 16KB
    __shared__ __align__(16) unsigned short a_sh[NSTEP][4][32][8];

    const int tid = threadIdx.x;
    const int w = tid >> 6;
    const int l = tid & 63;
    const int g = l >> 4;
    const int li = l & 15;
    const int row0 = blockIdx.x * 32;

    f32x4 acc[2][4];
#pragma unroll
    for (int m = 0; m < 2; ++m)
#pragma unroll
        for (int nn = 0; nn < 4; ++nn) acc[m][nn] = (f32x4)(0.0f);

    // stage the ENTIRE A panel: wave w stages steps [w*SPW, (w+1)*SPW), 2 gloads per step.
    // gload q of step t: lane i -> a_sh[t][2q + (i>>5)][i&31][0..7]
    //   global: A[row0 + (i&31)][k0 + (2q + (i>>5))*8 ..+8]
    {
        int grow = row0 + (l & 31);
        if (grow >= n) grow = n - 1;
        const int kgl = (l >> 5);
#pragma unroll
        for (int s = 0; s < SPW; ++s) {
            const int t = w * SPW + s;
            const int k0 = t * 32;
            const unsigned short* srcm = (k0 < KH) ? Aagg : Axin;
            const int kk = (k0 < KH) ? k0 : k0 - KH;
            const unsigned short* base = srcm + (size_t)grow * KH + kk;
#pragma unroll
            for (int q = 0; q < 2; ++q) {
                gload16(base + (2 * q + kgl) * 8, &a_sh[t][2 * q][0][0]);
            }
        }
    }
    __syncthreads();  // single drain: all stages complete

#pragma unroll
    for (int ks = 0; ks < NSTEP; ++ks) {
        const int k0 = ks * 32;
        bf16x8 bfr[4];
#pragma unroll
        for (int nn = 0; nn < 4; ++nn) {
            const unsigned short* bp = Wt + (size_t)(w * 64 + nn * 16 + li) * KC + k0 + 8 * g;
            bfr[nn] = __builtin_bit_cast(bf16x8, *(const uint4*)bp);
        }
        bf16x8 afr[2];
#pragma unroll
        for (int m = 0; m < 2; ++m)
            afr[m] = __builtin_bit_cast(bf16x8, *(const uint4*)&a_sh[ks][g][16 * m + li][0]);
#pragma unroll
        for (int nn = 0; nn < 4; ++nn)
#pragma unroll
            for (int m = 0; m < 2; ++m)
                acc[m][nn] = __builtin_amdgcn_mfma_f32_16x16x32_bf16(afr[m], bfr[nn], acc[m][nn], 0, 0, 0);
    }

    // bias
    float bv[4];
#pragma unroll
    for (int nn = 0; nn < 4; ++nn) bv[nn] = bl[w * 64 + nn * 16 + li];
#pragma unroll
    for (int m = 0; m < 2; ++m)
#pragma unroll
        for (int nn = 0; nn < 4; ++nn)
#pragma unroll
            for (int r = 0; r < 4; ++r) acc[m][nn][r] += bv[nn];

    // row sum-of-squares: reduce this wave's 64 cols (16-lane group shuffle)
    float ssp[2][4];
#pragma unroll
    for (int m = 0; m < 2; ++m)
#pragma unroll
        for (int r = 0; r < 4; ++r) {
            float s = 0.f;
#pragma unroll
            for (int nn = 0; nn < 4; ++nn) s += acc[m][nn][r] * acc[m][nn][r];
#pragma unroll
            for (int mk = 1; mk < 16; mk <<= 1) s += __shfl_xor(s, mk, 64);
            ssp[m][r] = s;
        }

    __syncthreads();  // A panel dead; reuse LDS for cross-wave reduction
    float* redp = (float*)&a_sh[0][0][0][0];  // [4][32] partials then [32] inv

    if (li == 0) {
#pragma unroll
        for (int m = 0; m < 2; ++m)
#pragma unroll
            for (int r = 0; r < 4; ++r) redp[w * 32 + 16 * m + 4 * g + r] = ssp[m][r];
    }
    __syncthreads();
    if (tid < 32) {
        float tot = redp[tid] + redp[32 + tid] + redp[64 + tid] + redp[96 + tid];
        redp[128 + tid] = 1.0f / fmaxf(sqrtf(tot), 1e-12f);
    }
    __syncthreads();

    float sc[4], sh[4];
    if (L0) {
#pragma unroll
        for (int nn = 0; nn < 4; ++nn) {
            int c = w * 64 + nn * 16 + li;
            float s = bng[c] * rsqrtf(bnv[c] + 1e-5f);
            sc[nn] = s;
            sh[nn] = bnb[c] - bnm[c] * s;
        }
    }
#pragma unroll
    for (int m = 0; m < 2; ++m) {
#pragma unroll
        for (int r = 0; r < 4; ++r) {
            int rl = 16 * m + 4 * g + r;
            int row = row0 + rl;
            if (row < n) {
                float inv = redp[128 + rl];
#pragma unroll
                for (int nn = 0; nn < 4; ++nn) {
                    int c = w * 64 + nn * 16 + li;
                    float v = acc[m][nn][r] * inv;
                    if (L0) {
                        v = fmaxf(v * sc[nn] + sh[nn], 0.f);
                        hout[(size_t)row * 256 + c] = f2bf(v);
                    } else {
                        fout[(size_t)row * 256 + c] = v;
                    }
                }
            }
        }
    }
}

// ---------------- launch ----------------
extern "C" void kernel_launch(void* const* d_in, const int* in_sizes, int n_in,
                              void* d_out, int out_size, void* d_ws, size_t ws_size,
                              hipStream_t stream) {
    const float* x   = (const float*)d_in[0];
    const void*  ei  = d_in[1];
    const float* Wl0 = (const float*)d_in[2];
    const float* bl0 = (const float*)d_in[3];
    const float* Wr0 = (const float*)d_in[4];
    const float* Wl1 = (const float*)d_in[5];
    const float* bl1 = (const float*)d_in[6];
    const float* Wr1 = (const float*)d_in[7];
    const float* bng = (const float*)d_in[8];
    const float* bnb = (const float*)d_in[9];
    const float* bnm = (const float*)d_in[10];
    const float* bnv = (const float*)d_in[11];
    float* out = (float*)d_out;

    const int N = NN;
    const int E = in_sizes[1] / 2;
    const int NB = (N + 1023) / 1024;  // 49 scan blocks

    char* wsp = (char*)d_ws;
    size_t o = 0;
    auto carve = [&](size_t bytes) {
        void* p = wsp + o;
        o = (o + bytes + 255) & ~(size_t)255;
        return p;
    };
    int* flag = (int*)carve(4);
    int* cnt  = (int*)carve((size_t)N * 4);
    int* off  = (int*)carve((size_t)(N + 1) * 4);
    int* pos  = (int*)carve((size_t)N * 4);
    int* bsum = (int*)carve((size_t)NB * 4);
    int* adj  = (int*)carve((size_t)E * 4);
    unsigned short* xbf  = (unsigned short*)carve((size_t)N * 128 * 2);
    unsigned short* agg0 = (unsigned short*)carve((size_t)N * 128 * 2);
    unsigned short* agg1 = xbf;  // reuse xbf region (dead after layer 0)
    unsigned short* hbf  = (unsigned short*)carve((size_t)N * 256 * 2);
    unsigned short* Wt0  = (unsigned short*)carve((size_t)256 * 256 * 2);
    unsigned short* Wt1  = (unsigned short*)carve((size_t)256 * 512 * 2);

    hipMemsetAsync(d_ws, 0, 256 + (size_t)N * 4, stream);

    detect_kernel<<<1, 256, 0, stream>>>((const int*)ei, flag);
    hist_kernel<<<(E + 255) / 256, 256, 0, stream>>>(ei, flag, cnt, E);
    scan_part<<<NB, 256, 0, stream>>>(cnt, bsum, N);
    scan_top<<<1, 64, 0, stream>>>(bsum, off, NB, N);
    scan_fin<<<NB, 256, 0, stream>>>(cnt, bsum, off, pos, N);
    fill_kernel<<<(E + 255) / 256, 256, 0, stream>>>(ei, flag, pos, adj, E);

    cvt_bf16<<<(N * 128 / 4 + 255) / 256, 256, 0, stream>>>(x, xbf, N * 128 / 4);
    prep_w<<<256, 256, 0, stream>>>(Wl0, Wr0, Wt0, 128);
    prep_w<<<256, 256, 0, stream>>>(Wl1, Wr1, Wt1, 256);

    agg_bf<2><<<(N + 3) / 4, 256, 0, stream>>>(xbf, off, adj, agg0, N);
    sage_mfma<128, true><<<(N + 31) / 32, 256, 0, stream>>>(
        agg0, xbf, Wt0, bl0, bng, bnb, bnm, bnv, hbf, nullptr, N);

    agg_bf<4><<<(N + 3) / 4, 256, 0, stream>>>(hbf, off, adj, agg1, N);
    sage_mfma<256, false><<<(N + 31) / 32, 256, 0, stream>>>(
        agg1, hbf, Wt1, bl1, bng, bnb, bnm, bnv, nullptr, out, N);
}

// Round 7
// 269.160 us; speedup vs baseline: 1.0259x; 1.0259x over previous
//
#include <hip/hip_runtime.h>

#define NN 50000

typedef __bf16 bf16x8 __attribute__((ext_vector_type(8)));
typedef float f32x4 __attribute__((ext_vector_type(4)));

__device__ __forceinline__ unsigned short f2bf(float f) {
    unsigned int u = __builtin_bit_cast(unsigned int, f);
    u += 0x7FFF + ((u >> 16) & 1);  // round-to-nearest-even
    return (unsigned short)(u >> 16);
}
__device__ __forceinline__ float bf2f(unsigned short h) {
    unsigned int u = ((unsigned int)h) << 16;
    return __builtin_bit_cast(float, u);
}
__device__ __forceinline__ void gload16(const void* g, void* l) {
    __builtin_amdgcn_global_load_lds(
        (const __attribute__((address_space(1))) unsigned int*)g,
        (__attribute__((address_space(3))) unsigned int*)l, 16, 0, 0);
}

// ---------------- edge dtype detection ----------------
__global__ void detect_kernel(const int* __restrict__ ei32, int* __restrict__ flag) {
    __shared__ int red[256];
    int tid = threadIdx.x;
    int o = 0;
    for (int i = tid; i < 4096; i += 256) o |= ei32[2 * i + 1];
    red[tid] = o;
    __syncthreads();
    for (int s = 128; s > 0; s >>= 1) {
        if (tid < s) red[tid] |= red[tid + s];
        __syncthreads();
    }
    if (tid == 0) *flag = (red[0] == 0) ? 1 : 0;
}

__device__ __forceinline__ int load_edge(const void* ei, int is64, long long idx) {
    return is64 ? (int)((const long long*)ei)[idx] : ((const int*)ei)[idx];
}

// ---------------- CSR build ----------------
__global__ void hist_kernel(const void* __restrict__ ei, const int* __restrict__ flag,
                            int* __restrict__ cnt, int E) {
    int e = blockIdx.x * blockDim.x + threadIdx.x;
    if (e >= E) return;
    int is64 = *flag;
    int dst = load_edge(ei, is64, (long long)E + e);
    atomicAdd(&cnt[dst], 1);
}

// pass 1: block b reduces cnt[b*1024 .. b*1024+1023] -> bsum[b]
__global__ void scan_part(const int* __restrict__ cnt, int* __restrict__ bsum, int n) {
    __shared__ int s[256];
    const int tid = threadIdx.x;
    const int i0 = blockIdx.x * 1024 + tid * 4;
    int sum = 0;
#pragma unroll
    for (int j = 0; j < 4; ++j) {
        int i = i0 + j;
        if (i < n) sum += cnt[i];
    }
    s[tid] = sum;
    __syncthreads();
    for (int o = 128; o > 0; o >>= 1) {
        if (tid < o) s[tid] += s[tid + o];
        __syncthreads();
    }
    if (tid == 0) bsum[blockIdx.x] = s[0];
}

// pass 2: one wave turns bsum[] (nb <= 64) into its exclusive scan; off[n] = total
__global__ void scan_top(int* __restrict__ bsum, int* __restrict__ off, int nb, int n) {
    const int lane = threadIdx.x & 63;
    int mine = (lane < nb) ? bsum[lane] : 0;
    int v = mine;
#pragma unroll
    for (int o = 1; o < 64; o <<= 1) {
        int t = __shfl_up(v, o, 64);
        if (lane >= o) v += t;
    }
    if (lane < nb) bsum[lane] = v - mine;  // exclusive prefix
    if (lane == 63) off[n] = v;            // grand total
}

// pass 3: block b scans its 1024 counts with base bsum[b]; writes off/pos
__global__ void scan_fin(const int* __restrict__ cnt, const int* __restrict__ bsum,
                         int* __restrict__ off, int* __restrict__ pos, int n) {
    __shared__ int s[256];
    const int tid = threadIdx.x;
    const int i0 = blockIdx.x * 1024 + tid * 4;
    int v[4];
    int sum = 0;
#pragma unroll
    for (int j = 0; j < 4; ++j) {
        int i = i0 + j;
        v[j] = (i < n) ? cnt[i] : 0;
        sum += v[j];
    }
    s[tid] = sum;
    __syncthreads();
    for (int o = 1; o < 256; o <<= 1) {
        int t = 0;
        if (tid >= o) t = s[tid - o];
        __syncthreads();
        s[tid] += t;
        __syncthreads();
    }
    int run = bsum[blockIdx.x] + s[tid] - sum;  // exclusive within grid
#pragma unroll
    for (int j = 0; j < 4; ++j) {
        int i = i0 + j;
        if (i < n) {
            off[i] = run;
            pos[i] = run;
            run += v[j];
        }
    }
}

__global__ void fill_kernel(const void* __restrict__ ei, const int* __restrict__ flag,
                            int* __restrict__ pos, int* __restrict__ adj, int E) {
    int e = blockIdx.x * blockDim.x + threadIdx.x;
    if (e >= E) return;
    int is64 = *flag;
    int src = load_edge(ei, is64, e);
    int dst = load_edge(ei, is64, (long long)E + e);
    int p = atomicAdd(&pos[dst], 1);
    adj[p] = src;
}

// ---------------- f32 -> bf16 convert ----------------
__global__ void cvt_bf16(const float* __restrict__ in, unsigned short* __restrict__ out, int n4) {
    int i = blockIdx.x * blockDim.x + threadIdx.x;
    if (i >= n4) return;
    float4 v = ((const float4*)in)[i];
    uint2 o;
    o.x = (unsigned int)f2bf(v.x) | ((unsigned int)f2bf(v.y) << 16);
    o.y = (unsigned int)f2bf(v.z) | ((unsigned int)f2bf(v.w) << 16);
    ((uint2*)out)[i] = o;
}

// ---------------- weight prep: Wt[c][k] = bf16([Wl; Wr][k][c]) ----------------
__global__ void prep_w(const float* __restrict__ Wl, const float* __restrict__ Wr,
                       unsigned short* __restrict__ Wt, int KH) {
    int c = blockIdx.x;  // 0..255
    int KC = 2 * KH;
    for (int k = threadIdx.x; k < KC; k += blockDim.x) {
        float v = (k < KH) ? Wl[(size_t)k * 256 + c] : Wr[(size_t)(k - KH) * 256 + c];
        Wt[(size_t)c * KC + k] = f2bf(v);
    }
}

// ---------------- mean aggregation, bf16 in/out, one wave per node ----------------
// Edge loop unrolled x4 with independent accumulators -> 4 row-gathers in flight (MLP=4).
template <int VPL>  // values per lane; F = 64*VPL
__global__ void agg_bf(const unsigned short* __restrict__ feat, const int* __restrict__ off,
                       const int* __restrict__ adj, unsigned short* __restrict__ out, int n) {
    int node = blockIdx.x * 4 + (threadIdx.x >> 6);
    if (node >= n) return;
    const int lane = threadIdx.x & 63;
    constexpr int F = 64 * VPL;
    const int s = off[node], e = off[node + 1];

    float a0[VPL] = {}, a1[VPL] = {}, a2[VPL] = {}, a3[VPL] = {};

    auto addrow = [&](float* acc, int src) {
        const unsigned short* p = feat + (size_t)src * F + lane * VPL;
        if constexpr (VPL == 2) {
            unsigned int v = *(const unsigned int*)p;
            acc[0] += bf2f((unsigned short)(v & 0xffff));
            acc[1] += bf2f((unsigned short)(v >> 16));
        } else {
            uint2 v = *(const uint2*)p;
            acc[0] += bf2f((unsigned short)(v.x & 0xffff));
            acc[1] += bf2f((unsigned short)(v.x >> 16));
            acc[2] += bf2f((unsigned short)(v.y & 0xffff));
            acc[3] += bf2f((unsigned short)(v.y >> 16));
        }
    };

    int j = s;
    for (; j + 4 <= e; j += 4) {
        int i0 = adj[j], i1 = adj[j + 1], i2 = adj[j + 2], i3 = adj[j + 3];
        addrow(a0, i0);
        addrow(a1, i1);
        addrow(a2, i2);
        addrow(a3, i3);
    }
    // tail (<=3), still independent accumulators
    {
        int rem = e - j;
        if (rem > 0) addrow(a0, adj[j]);
        if (rem > 1) addrow(a1, adj[j + 1]);
        if (rem > 2) addrow(a2, adj[j + 2]);
    }

    int deg = e - s;
    float inv = 1.0f / (float)(deg > 0 ? deg : 1);
#pragma unroll
    for (int k = 0; k < VPL; ++k) a0[k] = (a0[k] + a1[k] + a2[k] + a3[k]) * inv;

    if constexpr (VPL == 2) {
        unsigned int o = (unsigned int)f2bf(a0[0]) | ((unsigned int)f2bf(a0[1]) << 16);
        *(unsigned int*)(out + (size_t)node * F + lane * 2) = o;
    } else {
        uint2 o;
        o.x = (unsigned int)f2bf(a0[0]) | ((unsigned int)f2bf(a0[1]) << 16);
        o.y = (unsigned int)f2bf(a0[2]) | ((unsigned int)f2bf(a0[3]) << 16);
        *(uint2*)(out + (size_t)node * F + lane * 4) = o;
    }
}

// ---------------- fused SAGE MFMA GEMM (A AND B staged via global_load_lds) ----------
// C[64 x 256] per block, 4 waves, wave w owns cols [64w, 64w+64), acc 4x4 frags.
// Per BK=32 step: stage NEXT step's A tile (1 gload/wave) and B tile (4 gloads/wave)
// into the alternate LDS buffer, THEN compute current step from LDS only (no in-loop
// L2 dependency). Double-buffered, one barrier per step, static buffer indices.
// LDS: A 2x4KB + B 2x16KB = 40KB -> 4 blocks/CU.
template <int KH, bool L0>
__global__ __launch_bounds__(256, 4) void sage_mfma(
    const unsigned short* __restrict__ Aagg, const unsigned short* __restrict__ Axin,
    const unsigned short* __restrict__ Wt, const float* __restrict__ bl,
    const float* __restrict__ bng, const float* __restrict__ bnb,
    const float* __restrict__ bnm, const float* __restrict__ bnv,
    unsigned short* __restrict__ hout, float* __restrict__ fout, int n) {
    constexpr int KC = 2 * KH;
    constexpr int NSTEP = KC / 32;  // 8 (L0), 16 (L1); always even
    __shared__ __align__(16) unsigned short a_sh[2][4][64][8];   // [buf][kgrp][row][8]  8KB
    __shared__ __align__(16) unsigned short b_sh[2][4][256][8];  // [buf][kgrp][col][8] 32KB

    const int tid = threadIdx.x;
    const int w = tid >> 6;
    const int l = tid & 63;
    const int g = l >> 4;
    const int li = l & 15;
    const int row0 = blockIdx.x * 64;
    int srow = row0 + l;
    if (srow >= n) srow = n - 1;

    f32x4 acc[4][4];
#pragma unroll
    for (int m = 0; m < 4; ++m)
#pragma unroll
        for (int nn = 0; nn < 4; ++nn) acc[m][nn] = (f32x4)(0.0f);

    const unsigned short* bsrc = Wt + (size_t)(w * 64 + l) * KC;  // per-lane B row base

    // stage step t into buffer buf: A rows via wave-kgrp split, B cols via per-wave 64-col slice
    auto stage = [&](int buf, int t) {
        const int k0 = t * 32;
        const unsigned short* srcm = (k0 < KH) ? Aagg : Axin;
        const int kk = (k0 < KH) ? k0 : k0 - KH;
        gload16(srcm + (size_t)srow * KH + kk + w * 8, &a_sh[buf][w][0][0]);  // lane l -> row l
#pragma unroll
        for (int q = 0; q < 4; ++q)  // kgrp q: lane l -> col w*64+l
            gload16(bsrc + k0 + q * 8, &b_sh[buf][q][w * 64][0]);
    };

    auto compute = [&](int buf, int ks) {
        bf16x8 bfr[4];
#pragma unroll
        for (int nn = 0; nn < 4; ++nn)
            bfr[nn] = __builtin_bit_cast(bf16x8, *(const uint4*)&b_sh[buf][g][w * 64 + nn * 16 + li][0]);
        bf16x8 afr[4];
#pragma unroll
        for (int m = 0; m < 4; ++m)
            afr[m] = __builtin_bit_cast(bf16x8, *(const uint4*)&a_sh[buf][g][16 * m + li][0]);
#pragma unroll
        for (int nn = 0; nn < 4; ++nn)
#pragma unroll
            for (int m = 0; m < 4; ++m)
                acc[m][nn] = __builtin_amdgcn_mfma_f32_16x16x32_bf16(afr[m], bfr[nn], acc[m][nn], 0, 0, 0);
    };

    stage(0, 0);
    __syncthreads();  // buf0 ready
    for (int ks = 0; ks < NSTEP; ks += 2) {
        stage(1, ks + 1);      // issue next-step loads first (async, in flight over compute)
        compute(0, ks);
        __syncthreads();       // buf1 ready, buf0 free
        if (ks + 2 < NSTEP) stage(0, ks + 2);
        compute(1, ks + 1);
        __syncthreads();       // buf0 ready, buf1 free
    }

    // bias
    float bv[4];
#pragma unroll
    for (int nn = 0; nn < 4; ++nn) bv[nn] = bl[w * 64 + nn * 16 + li];
#pragma unroll
    for (int m = 0; m < 4; ++m)
#pragma unroll
        for (int nn = 0; nn < 4; ++nn)
#pragma unroll
            for (int r = 0; r < 4; ++r) acc[m][nn][r] += bv[nn];

    // row sum-of-squares: reduce this wave's 64 cols (16-lane group shuffle)
    float ssp[4][4];
#pragma unroll
    for (int m = 0; m < 4; ++m)
#pragma unroll
        for (int r = 0; r < 4; ++r) {
            float s = 0.f;
#pragma unroll
            for (int nn = 0; nn < 4; ++nn) s += acc[m][nn][r] * acc[m][nn][r];
#pragma unroll
            for (int mk = 1; mk < 16; mk <<= 1) s += __shfl_xor(s, mk, 64);
            ssp[m][r] = s;
        }

    __syncthreads();  // LDS dead; reuse for cross-wave reduction
    float* redp = (float*)&a_sh[0][0][0][0];  // [4][64] partials then [64] inv

    if (li == 0) {
#pragma unroll
        for (int m = 0; m < 4; ++m)
#pragma unroll
            for (int r = 0; r < 4; ++r) redp[w * 64 + 16 * m + 4 * g + r] = ssp[m][r];
    }
    __syncthreads();
    if (tid < 64) {
        float tot = redp[tid] + redp[64 + tid] + redp[128 + tid] + redp[192 + tid];
        redp[256 + tid] = 1.0f / fmaxf(sqrtf(tot), 1e-12f);
    }
    __syncthreads();

    float sc[4], sh[4];
    if (L0) {
#pragma unroll
        for (int nn = 0; nn < 4; ++nn) {
            int c = w * 64 + nn * 16 + li;
            float s = bng[c] * rsqrtf(bnv[c] + 1e-5f);
            sc[nn] = s;
            sh[nn] = bnb[c] - bnm[c] * s;
        }
    }
#pragma unroll
    for (int m = 0; m < 4; ++m) {
#pragma unroll
        for (int r = 0; r < 4; ++r) {
            int rl = 16 * m + 4 * g + r;
            int row = row0 + rl;
            if (row < n) {
                float inv = redp[256 + rl];
#pragma unroll
                for (int nn = 0; nn < 4; ++nn) {
                    int c = w * 64 + nn * 16 + li;
                    float v = acc[m][nn][r] * inv;
                    if (L0) {
                        v = fmaxf(v * sc[nn] + sh[nn], 0.f);
                        hout[(size_t)row * 256 + c] = f2bf(v);
                    } else {
                        fout[(size_t)row * 256 + c] = v;
                    }
                }
            }
        }
    }
}

// ---------------- launch ----------------
extern "C" void kernel_launch(void* const* d_in, const int* in_sizes, int n_in,
                              void* d_out, int out_size, void* d_ws, size_t ws_size,
                              hipStream_t stream) {
    const float* x   = (const float*)d_in[0];
    const void*  ei  = d_in[1];
    const float* Wl0 = (const float*)d_in[2];
    const float* bl0 = (const float*)d_in[3];
    const float* Wr0 = (const float*)d_in[4];
    const float* Wl1 = (const float*)d_in[5];
    const float* bl1 = (const float*)d_in[6];
    const float* Wr1 = (const float*)d_in[7];
    const float* bng = (const float*)d_in[8];
    const float* bnb = (const float*)d_in[9];
    const float* bnm = (const float*)d_in[10];
    const float* bnv = (const float*)d_in[11];
    float* out = (float*)d_out;

    const int N = NN;
    const int E = in_sizes[1] / 2;
    const int NB = (N + 1023) / 1024;  // 49 scan blocks

    char* wsp = (char*)d_ws;
    size_t o = 0;
    auto carve = [&](size_t bytes) {
        void* p = wsp + o;
        o = (o + bytes + 255) & ~(size_t)255;
        return p;
    };
    int* flag = (int*)carve(4);
    int* cnt  = (int*)carve((size_t)N * 4);
    int* off  = (int*)carve((size_t)(N + 1) * 4);
    int* pos  = (int*)carve((size_t)N * 4);
    int* bsum = (int*)carve((size_t)NB * 4);
    int* adj  = (int*)carve((size_t)E * 4);
    unsigned short* xbf  = (unsigned short*)carve((size_t)N * 128 * 2);
    unsigned short* agg0 = (unsigned short*)carve((size_t)N * 128 * 2);
    unsigned short* agg1 = xbf;  // reuse xbf region (dead after layer 0)
    unsigned short* hbf  = (unsigned short*)carve((size_t)N * 256 * 2);
    unsigned short* Wt0  = (unsigned short*)carve((size_t)256 * 256 * 2);
    unsigned short* Wt1  = (unsigned short*)carve((size_t)256 * 512 * 2);

    hipMemsetAsync(d_ws, 0, 256 + (size_t)N * 4, stream);

    detect_kernel<<<1, 256, 0, stream>>>((const int*)ei, flag);
    hist_kernel<<<(E + 255) / 256, 256, 0, stream>>>(ei, flag, cnt, E);
    scan_part<<<NB, 256, 0, stream>>>(cnt, bsum, N);
    scan_top<<<1, 64, 0, stream>>>(bsum, off, NB, N);
    scan_fin<<<NB, 256, 0, stream>>>(cnt, bsum, off, pos, N);
    fill_kernel<<<(E + 255) / 256, 256, 0, stream>>>(ei, flag, pos, adj, E);

    cvt_bf16<<<(N * 128 / 4 + 255) / 256, 256, 0, stream>>>(x, xbf, N * 128 / 4);
    prep_w<<<256, 256, 0, stream>>>(Wl0, Wr0, Wt0, 128);
    prep_w<<<256, 256, 0, stream>>>(Wl1, Wr1, Wt1, 256);

    agg_bf<2><<<(N + 3) / 4, 256, 0, stream>>>(xbf, off, adj, agg0, N);
    sage_mfma<128, true><<<(N + 63) / 64, 256, 0, stream>>>(
        agg0, xbf, Wt0, bl0, bng, bnb, bnm, bnv, hbf, nullptr, N);

    agg_bf<4><<<(N + 3) / 4, 256, 0, stream>>>(hbf, off, adj, agg1, N);
    sage_mfma<256, false><<<(N + 63) / 64, 256, 0, stream>>>(
        agg1, hbf, Wt1, bl1, bng, bnb, bnm, bnv, nullptr, out, N);
}